// Round 6
// baseline (3293.328 us; speedup 1.0000x reference)
//
#include <hip/hip_runtime.h>
#include <cstring>

#define NQ 16
#define NLAYERS 8
#define BATCHN 512
#define GROUPB 128                 // batches per L3-resident group (64 MiB slice)
#define NGROUP (BATCHN/GROUPB)
#define LB 13
#define NLOC (1<<LB)
#define NCHUNK (1<<(NQ-LB))
#define NTHREADS 512

typedef unsigned u32;

// Pass p: [prev-layer 3 deferred Rots] -> [tau = deferred CNOTs folded into LDS gather,
// with chunk-dependent affine masks for global-control gates] -> [13 local Rots]
// -> [applied-CNOT fold on write].
struct PD {
  int layerA, layerB, mode, b0;   // mode: 0 mid, 1 init, 2 fin
  int qop[13];        // qubit at local position
  int glb[3];         // global (chunk) qubits, ascending
  int r1dPos[2];      // R1 tile-dir positions
  int r1dQ[2];        // their qubits
  int r1lQ;           // R1 lane-gate qubit (at tid bit 5)
  int r1f[9];         // R1 thread-bit -> position (bits0-4 lowest free, bit5 = lane pos)
  u32 tinv[13];       // tau^{-1} local masks (raw)
  u32 cinv[13];       // mid: (tau^{-1} o A^{-1}) local; fin: full fwd masks
  u32 tL[13];         // Lmap(tinv)
  u32 cL[13];         // Lmap(cinv) (mid passes)
  u32 tCkL[3];        // chunk-bit affine masks of tau^{-1} (L-mapped local part)
  u32 fCk[3];         // readout: forward tau image of chunk basis (full 16-bit)
  u32 r1em[9];        // global gather masks (1<<qubit)
  u32 r1eL[9];        // LDS write masks (Lmap(1<<pos))
  u32 r1dm[2];        // dir global masks
  u32 r1dLm[2];       // dir LDS masks
};

template<int J>
__device__ __forceinline__ void gate16(float2 (&a)[16],
  float M0r,float M0i,float M1r,float M1i,float M2r,float M2i,float M3r,float M3i){
  #pragma unroll
  for (int i=0;i<16;i++){
    if ((i>>J)&1) continue;
    const int i1 = i|(1<<J);
    float ar=a[i].x, ai=a[i].y, br=a[i1].x, bi=a[i1].y;
    a[i].x  = M0r*ar - M0i*ai + M1r*br - M1i*bi;
    a[i].y  = M0r*ai + M0i*ar + M1r*bi + M1i*br;
    a[i1].x = M2r*ar - M2i*ai + M3r*br - M3i*bi;
    a[i1].y = M2r*ai + M2i*ar + M3r*bi + M3i*br;
  }
}

__device__ __forceinline__ void lane_gate16(float2 (&a)[16], int tid, int j,
  float r0,float i0,float r1,float i1,float r2,float i2,float r3,float i3){
  int bit = (tid >> j) & 1;
  float cAr = bit? r3 : r0, cAi = bit? i3 : i0;
  float cBr = bit? r2 : r1, cBi = bit? i2 : i1;
  #pragma unroll
  for (int i=0;i<16;i++){
    float tx = __shfl_xor(a[i].x, 1<<j);
    float ty = __shfl_xor(a[i].y, 1<<j);
    float ax = a[i].x, ay = a[i].y;
    a[i].x = cAr*ax - cAi*ay + cBr*tx - cBi*ty;
    a[i].y = cAr*ay + cAi*ax + cBr*ty + cBi*tx;
  }
}

#define APPLY16(J, SRC) { \
  int _s = (SRC); \
  float r0_=__shfl(mm0,_s), i0_=__shfl(mm1,_s), r1_=__shfl(mm2,_s), i1_=__shfl(mm3,_s); \
  float r2_=__shfl(mm4,_s), i2_=__shfl(mm5,_s), r3_=__shfl(mm6,_s), i3_=__shfl(mm7,_s); \
  gate16<J>(a, r0_,i0_,r1_,i1_,r2_,i2_,r3_,i3_); }

#define LANE16(J, SRC) { \
  int _s = (SRC); \
  float r0_=__shfl(mm0,_s), i0_=__shfl(mm1,_s), r1_=__shfl(mm2,_s), i1_=__shfl(mm3,_s); \
  float r2_=__shfl(mm4,_s), i2_=__shfl(mm5,_s), r3_=__shfl(mm6,_s), i3_=__shfl(mm7,_s); \
  lane_gate16(a, tid, (J), r0_,i0_,r1_,i1_,r2_,i2_,r3_,i3_); }

// NOTE: second arg relaxed 4 -> 2. With (512,4) hipcc capped VGPRs at 64 ->
// heavy scratch spill (WRITE_SIZE 3x ideal, VGPR_Count=64 in round 5).
// Occupancy is LDS-bound at 2 blocks/CU regardless, so the tight cap bought nothing.
__global__ __launch_bounds__(NTHREADS, 2)
void qpass(const float* __restrict__ x, const float* __restrict__ w,
           float2* __restrict__ state, float* __restrict__ out, PD pd)
{
  __shared__ __align__(16) float2 st[NLOC];   // 64 KB
  const int tid = threadIdx.x;
  const u32 chunk = blockIdx.x;
  const int b = pd.b0 + blockIdx.y;
  float2* __restrict__ gst = state + ((size_t)b << NQ);

  // per-lane Rot matrices: lanes 0-15 = layerA (prev), 16-31 = layerB (cur)
  float mm0,mm1,mm2,mm3,mm4,mm5,mm6,mm7;
  {
    int lane = tid & 63;
    int q = lane & 15;
    int lay = ((lane>>4)&1) ? pd.layerB : pd.layerA;
    if (lay < 0) lay = 0;
    float phi = w[(lay*NQ+q)*3+0], th = w[(lay*NQ+q)*3+1], om = w[(lay*NQ+q)*3+2];
    float sh, ch; sincosf(0.5f*th, &sh, &ch);
    float spo, cpo; sincosf(-0.5f*(phi+om), &spo, &cpo);
    float smo, cmo; sincosf(-0.5f*(phi-om), &smo, &cmo);
    mm0 =  cpo*ch; mm1 =  spo*ch;
    mm2 = -cmo*sh; mm3 =  smo*sh;
    mm4 =  cmo*sh; mm5 =  smo*sh;
    mm6 =  cpo*ch; mm7 = -spo*ch;
  }

  // chunk-dependent affine part of tau^{-1} (L-mapped)
  u32 ckL = 0;
  if (chunk & 1) ckL ^= pd.tCkL[0];
  if (chunk & 2) ckL ^= pd.tCkL[1];
  if (chunk & 4) ckL ^= pd.tCkL[2];

  float2 a[16];

  // ================= R1: coalesced global gather + 3 prev-layer deferred Rots =====
  if (pd.mode != 1){
    u32 ebase = 0, lbL = 0;
    #pragma unroll
    for (int j=0;j<9;j++) if ((tid>>j)&1){ ebase ^= pd.r1em[j]; lbL ^= pd.r1eL[j]; }
    #pragma unroll
    for (int j=0;j<3;j++) if ((chunk>>j)&1) ebase ^= 1u<<pd.glb[j];
    #pragma unroll
    for (int g=0; g<4; g++){
      u32 full = ebase ^ ((g&1)?pd.r1dm[0]:0u) ^ (((g>>1)&1)?pd.r1dm[1]:0u);
      const float4* gp = (const float4*)(gst + full);
      float4 v0 = gp[0], v1 = gp[1];
      a[g*4+0] = make_float2(v0.x,v0.y); a[g*4+1] = make_float2(v0.z,v0.w);
      a[g*4+2] = make_float2(v1.x,v1.y); a[g*4+3] = make_float2(v1.z,v1.w);
    }
    APPLY16(2, pd.r1dQ[0]);
    APPLY16(3, pd.r1dQ[1]);
    LANE16(5, pd.r1lQ);

    if (pd.mode == 2){
      // -------- readout: |amp|^2, full forward masks in cinv; chunk via fCk --------
      float acc[NQ];
      #pragma unroll
      for (int q=0;q<NQ;q++) acc[q]=0.f;
      u32 nb = 0;
      #pragma unroll
      for (int j=0;j<9;j++) if ((tid>>j)&1) nb ^= pd.cinv[pd.r1f[j]];
      #pragma unroll
      for (int j=0;j<3;j++) if ((chunk>>j)&1) nb ^= pd.fCk[j];
      u32 cd0 = pd.cinv[pd.r1dPos[0]], cd1 = pd.cinv[pd.r1dPos[1]];
      #pragma unroll
      for (int g=0; g<4; g++){
        u32 n0 = nb ^ ((g&1)?cd0:0u) ^ (((g>>1)&1)?cd1:0u);
        #pragma unroll
        for (int e=0;e<4;e++){
          u32 n = n0 ^ ((e&1)?pd.cinv[0]:0u) ^ (((e>>1)&1)?pd.cinv[1]:0u);
          float2 v = a[g*4+e];
          float p = v.x*v.x + v.y*v.y;
          #pragma unroll
          for (int q=0;q<NQ;q++) acc[q] += ((n>>q)&1u) ? -p : p;
        }
      }
      #pragma unroll
      for (int q=0;q<NQ;q++){
        float v = acc[q];
        #pragma unroll
        for (int off=32; off; off>>=1) v += __shfl_xor(v, off);
        if ((tid & 63) == 0) atomicAdd(&out[b*NQ+q], v);
      }
      return;
    }

    // write tile to LDS (logical pre-tau layout)
    #pragma unroll
    for (int g=0; g<4; g++){
      u32 mL = lbL ^ ((g&1)?pd.r1dLm[0]:0u) ^ (((g>>1)&1)?pd.r1dLm[1]:0u);
      ((float4*)st)[(mL>>1)  ] = make_float4(a[g*4+0].x,a[g*4+0].y,a[g*4+1].x,a[g*4+1].y);
      ((float4*)st)[(mL>>1)+1] = make_float4(a[g*4+2].x,a[g*4+2].y,a[g*4+3].x,a[g*4+3].y);
    }
    __syncthreads();
  }

  // ================= R2: 10 gates (2 e + 2 dir + 6 lane) =================
  u32 sbL = ckL;
  #pragma unroll
  for (int j=0;j<9;j++) if ((tid>>j)&1) sbL ^= pd.tL[2+j];
  const u32 Ltd0 = pd.tL[11], Ltd1 = pd.tL[12], Le0 = pd.tL[0], Le1 = pd.tL[1];

  if (pd.mode == 1){
    // embed: product state directly in R2 layout (tau = identity at p=0)
    float ca[NQ], sa[NQ];
    #pragma unroll
    for (int q=0;q<NQ;q++){
      float aa = 1.57079632679489662f * x[b*NQ+q];
      sincosf(aa, &sa[q], &ca[q]);
    }
    float vt = 1.f;
    #pragma unroll
    for (int j=0;j<9;j++){ int q = pd.qop[2+j]; vt *= ((tid>>j)&1)? sa[q] : ca[q]; }
    #pragma unroll
    for (int j=0;j<3;j++){ int q = pd.glb[j]; vt *= ((chunk>>j)&1)? sa[q] : ca[q]; }
    float c0 = ca[pd.qop[0]], s0 = sa[pd.qop[0]], c1 = ca[pd.qop[1]], s1 = sa[pd.qop[1]];
    float cd0 = ca[pd.qop[11]], sd0 = sa[pd.qop[11]];
    float cd1 = ca[pd.qop[12]], sd1 = sa[pd.qop[12]];
    #pragma unroll
    for (int g=0; g<4; g++){
      float vg = vt * ((g&1)? sd0 : cd0) * (((g>>1)&1)? sd1 : cd1);
      a[g*4+0] = make_float2(vg*c0*c1, 0.f);
      a[g*4+1] = make_float2(vg*s0*c1, 0.f);
      a[g*4+2] = make_float2(vg*c0*s1, 0.f);
      a[g*4+3] = make_float2(vg*s0*s1, 0.f);
    }
  } else {
    #pragma unroll
    for (int g=0; g<4; g++){
      u32 sL = sbL ^ ((g&1)?Ltd0:0u) ^ (((g>>1)&1)?Ltd1:0u);
      a[g*4+0] = st[sL];
      a[g*4+1] = st[sL^Le0];
      a[g*4+2] = st[sL^Le1];
      a[g*4+3] = st[sL^Le0^Le1];
    }
  }

  APPLY16(0, 16+pd.qop[0]);  APPLY16(1, 16+pd.qop[1]);
  APPLY16(2, 16+pd.qop[11]); APPLY16(3, 16+pd.qop[12]);
  #pragma unroll
  for (int j=0;j<6;j++){
    LANE16(j, 16+pd.qop[2+j]);
  }

  #pragma unroll
  for (int g=0; g<4; g++){
    u32 sL = sbL ^ ((g&1)?Ltd0:0u) ^ (((g>>1)&1)?Ltd1:0u);
    st[sL]         = a[g*4+0];
    st[sL^Le0]     = a[g*4+1];
    st[sL^Le1]     = a[g*4+2];
    st[sL^Le0^Le1] = a[g*4+3];
  }
  __syncthreads();

  // ================= R2b: 3 gates (dirs at pos 8,9 + lane gate at pos 10) =====
  // thread bits: bit0->pos10, bits1..6->pos2..7, bit7->pos11, bit8->pos12
  {
    u32 s2L = ckL;
    if (tid & 1) s2L ^= pd.tL[10];
    #pragma unroll
    for (int j=1;j<7;j++) if ((tid>>j)&1) s2L ^= pd.tL[1+j];
    if ((tid>>7)&1) s2L ^= pd.tL[11];
    if ((tid>>8)&1) s2L ^= pd.tL[12];
    const u32 LD0 = pd.tL[8], LD1 = pd.tL[9];
    #pragma unroll
    for (int g=0; g<4; g++){
      u32 sL = s2L ^ ((g&1)?LD0:0u) ^ (((g>>1)&1)?LD1:0u);
      a[g*4+0] = st[sL];
      a[g*4+1] = st[sL^Le0];
      a[g*4+2] = st[sL^Le1];
      a[g*4+3] = st[sL^Le0^Le1];
    }
    APPLY16(2, 16+pd.qop[8]); APPLY16(3, 16+pd.qop[9]);
    LANE16(0, 16+pd.qop[10]);
    #pragma unroll
    for (int g=0; g<4; g++){
      u32 sL = s2L ^ ((g&1)?LD0:0u) ^ (((g>>1)&1)?LD1:0u);
      st[sL]         = a[g*4+0];
      st[sL^Le0]     = a[g*4+1];
      st[sL^Le1]     = a[g*4+2];
      st[sL^Le0^Le1] = a[g*4+3];
    }
    __syncthreads();
  }

  // ================= R3: coalesced stage-out, (tau^-1 o A^-1) fold on LDS read =====
  {
    u32 ctL = ckL, etid = 0;
    #pragma unroll
    for (int j=0;j<9;j++) if ((tid>>j)&1){ ctL ^= pd.cL[2+j]; etid ^= 1u<<pd.qop[2+j]; }
    #pragma unroll
    for (int j=0;j<3;j++) if ((chunk>>j)&1) etid ^= 1u<<pd.glb[j];
    const u32 Lc0 = pd.cL[0], Lc1 = pd.cL[1];
    const u32 Lc11 = pd.cL[11], Lc12 = pd.cL[12];
    const u32 q11 = 1u<<pd.qop[11], q12 = 1u<<pd.qop[12];
    #pragma unroll
    for (int j=0;j<4;j++){
      u32 srcL  = ctL  ^ ((j&1)?Lc11:0u) ^ (((j>>1)&1)?Lc12:0u);
      u32 ofull = etid ^ ((j&1)?q11:0u)  ^ (((j>>1)&1)?q12:0u);
      float2 vv0 = st[srcL];
      float2 vv1 = st[srcL^Lc0];
      float2 vv2 = st[srcL^Lc1];
      float2 vv3 = st[srcL^Lc0^Lc1];
      float4* gp = (float4*)(gst + ofull);
      gp[0] = make_float4(vv0.x,vv0.y,vv1.x,vv1.y);
      gp[1] = make_float4(vv2.x,vv2.y,vv3.x,vv3.y);
    }
  }
}

// ======================= host side =======================
// Hand-verified schedule: globals high (coalesced), deferred targets always local
// in the next pass; global-CONTROL deferred gates handled via tCkL chunk masks.
static const int Gs[9][3] = {
  {13,14,15},{8,10,12},{11,13,15},{8,9,10},{7,11,15},{8,9,10},{11,12,13},{8,9,10},{13,14,15}
};
static const int Dlen[8] = {4,5,7,9,8,10,8,6};
static const int Dl[8][10] = {
  {12,13,14,15,0,0,0,0,0,0},
  {6,8,10,12,14,0,0,0,0,0},
  {8,10,11,12,13,14,15,0,0,0},
  {4,5,6,8,9,10,12,13,14,0},
  {2,6,7,10,11,12,13,15,0,0},
  {2,3,4,8,9,10,12,13,14,15},
  {4,5,6,11,12,13,14,15,0,0},
  {0,1,2,8,9,10,0,0,0,0},
};

static inline u32 apply_cnot_idx(u32 v, int c, int t){ return v ^ (((v>>c)&1u)<<t); }
static inline u32 h_swz(u32 q){ return q ^ ((q>>3)&7u); }
static inline u32 h_Lmap(u32 m){ return (h_swz(m>>2)<<2) | (m&3u); }

extern "C" void kernel_launch(void* const* d_in, const int* in_sizes, int n_in,
                              void* d_out, int out_size, void* d_ws, size_t ws_size,
                              hipStream_t stream)
{
  (void)in_sizes; (void)n_in; (void)ws_size;
  const float* x = (const float*)d_in[0];
  const float* w = (const float*)d_in[1];
  float* out = (float*)d_out;
  float2* state = (float2*)d_ws;   // 512 * 65536 * 8B = 256 MiB

  hipMemsetAsync(d_out, 0, (size_t)out_size*sizeof(float), stream);

  for (int grp=0; grp<NGROUP; grp++){
    for (int p=0; p<9; p++){
      PD pd; memset(&pd, 0, sizeof(pd));
      pd.layerA = p-1;
      pd.layerB = (p<=7)? p : -1;
      pd.mode = (p==0)? 1 : ((p==8)? 2 : 0);
      pd.b0 = grp*GROUPB;

      u32 gm = 0;
      for (int i=0;i<3;i++){ pd.glb[i] = Gs[p][i]; gm |= 1u<<Gs[p][i]; }
      int np=0;
      for (int q=0;q<16;q++) if (!((gm>>q)&1u)) pd.qop[np++] = q;

      // R1 geometry (prev-layer deferred Rot gates)
      if (p >= 1){
        int pos[3], qq[3];
        for (int i=0;i<3;i++){
          int q = Gs[p-1][i]; qq[i] = q;
          int c=0; for (int k=0;k<q;k++) if ((gm>>k)&1u) c++;
          pos[i] = q - c;
        }
        for (int i=0;i<3;i++) for (int k=i+1;k<3;k++)
          if (pos[k] < pos[i]){ int t=pos[i];pos[i]=pos[k];pos[k]=t; t=qq[i];qq[i]=qq[k];qq[k]=t; }
        pd.r1lQ = qq[0];
        pd.r1dPos[0]=pos[1]; pd.r1dQ[0]=qq[1];
        pd.r1dPos[1]=pos[2]; pd.r1dQ[1]=qq[2];
        int free_[9], nf=0;
        for (int pp=2; pp<13; pp++)
          if (pp!=pos[0] && pp!=pos[1] && pp!=pos[2]) free_[nf++]=pp;   // 8 entries
        for (int j=0;j<5;j++) pd.r1f[j]=free_[j];   // bits 0-4: lowest positions
        pd.r1f[5]=pos[0];                            // bit 5: lane-gate position
        for (int j=0;j<3;j++) pd.r1f[6+j]=free_[5+j];
      } else {
        pd.r1lQ = 0;
        pd.r1dPos[0]=11; pd.r1dQ[0]=0;
        pd.r1dPos[1]=12; pd.r1dQ[1]=0;
        for (int j=0;j<5;j++) pd.r1f[j]=2+j;
        pd.r1f[5]=10; pd.r1f[6]=7; pd.r1f[7]=8; pd.r1f[8]=9;
      }

      // tinv: tau^{-1} on local basis (deferred CNOTs of layer p-1, reverse order)
      if (p == 0){
        for (int bp=0;bp<13;bp++) pd.tinv[bp] = 1u<<bp;
        for (int j=0;j<3;j++) pd.tCkL[j] = 0u;
      } else {
        int r = p;  // layer (p-1) has r = p
        for (int bp=0;bp<13;bp++){
          u32 v = 1u<<pd.qop[bp];
          for (int i=Dlen[p-1]-1;i>=0;i--){ int c=Dl[p-1][i]; v = apply_cnot_idx(v, c, (c+r)&15); }
          u32 lv=0; for (int rr=0;rr<13;rr++) lv |= ((v>>pd.qop[rr])&1u)<<rr;
          pd.tinv[bp] = lv;
        }
        // chunk-basis affine part: image of chunk qubit under tau^{-1}, local component
        for (int j=0;j<3;j++){
          u32 v = 1u<<pd.glb[j];
          for (int i=Dlen[p-1]-1;i>=0;i--){ int c=Dl[p-1][i]; v = apply_cnot_idx(v, c, (c+r)&15); }
          v &= ~(1u<<pd.glb[j]);      // chunk bit passes through; keep local part
          u32 lv=0; for (int rr=0;rr<13;rr++) lv |= ((v>>pd.qop[rr])&1u)<<rr;
          pd.tCkL[j] = h_Lmap(lv);
        }
      }

      // cinv
      if (p <= 7){
        int r = p+1;
        bool inD[16]; for (int i=0;i<16;i++) inD[i]=false;
        for (int i=0;i<Dlen[p];i++) inD[Dl[p][i]] = true;
        int A[16], na=0;
        for (int i=0;i<16;i++) if (!inD[i]) A[na++]=i;
        for (int bp=0;bp<13;bp++){
          u32 v = 1u<<pd.qop[bp];
          for (int i=na-1;i>=0;i--){ int c=A[i]; v = apply_cnot_idx(v, c, (c+r)&15); }
          if (p >= 1){
            int rp = p;
            for (int i=Dlen[p-1]-1;i>=0;i--){ int c=Dl[p-1][i]; v = apply_cnot_idx(v, c, (c+rp)&15); }
          }
          u32 lv=0; for (int rr=0;rr<13;rr++) lv |= ((v>>pd.qop[rr])&1u)<<rr;
          pd.cinv[bp] = lv;
        }
        for (int j=0;j<3;j++) pd.fCk[j] = 0u;
      } else {
        // readout: full forward tau (D_7 ascending, r=8), uncompressed 16-bit
        for (int bp=0;bp<13;bp++){
          u32 v = 1u<<pd.qop[bp];
          for (int i=0;i<Dlen[7];i++){ int c=Dl[7][i]; v = apply_cnot_idx(v, c, (c+8)&15); }
          pd.cinv[bp] = v;
        }
        for (int j=0;j<3;j++){
          u32 v = 1u<<pd.glb[j];
          for (int i=0;i<Dlen[7];i++){ int c=Dl[7][i]; v = apply_cnot_idx(v, c, (c+8)&15); }
          pd.fCk[j] = v;
        }
      }

      // L-mapped precomputes
      for (int k=0;k<13;k++){
        pd.tL[k] = h_Lmap(pd.tinv[k]);
        pd.cL[k] = (p<=7) ? h_Lmap(pd.cinv[k]) : 0u;
      }
      for (int j=0;j<9;j++){
        pd.r1em[j] = 1u<<pd.qop[pd.r1f[j]];
        pd.r1eL[j] = h_Lmap(1u<<pd.r1f[j]);
      }
      for (int j=0;j<2;j++){
        pd.r1dm[j]  = 1u<<pd.qop[pd.r1dPos[j]];
        pd.r1dLm[j] = h_Lmap(1u<<pd.r1dPos[j]);
      }

      hipLaunchKernelGGL(qpass, dim3(NCHUNK, GROUPB), dim3(NTHREADS), 0, stream,
                         x, w, state, out, pd);
    }
  }
}

// Round 7
// 2897.542 us; speedup vs baseline: 1.1366x; 1.1366x over previous
//
#include <hip/hip_runtime.h>
#include <cstring>

#define NQ 16
#define NLAYERS 8
#define BATCHN 512
#define GROUPB 128                 // batches per L3-resident group (64 MiB slice)
#define NGROUP (BATCHN/GROUPB)
#define LB 13
#define NLOC (1<<LB)
#define NCHUNK (1<<(NQ-LB))
#define NTHREADS 512

typedef unsigned u32;

// Pass p: [prev-layer 3 deferred Rots] -> [tau = deferred CNOTs folded into LDS gather,
// with chunk-dependent affine masks for global-control gates] -> [13 local Rots]
// -> [applied-CNOT fold on write].
struct PD {
  int layerA, layerB, mode, b0;   // mode: 0 mid, 1 init, 2 fin
  int qop[13];        // qubit at local position
  int glb[3];         // global (chunk) qubits, ascending
  int r1dPos[2];      // R1 tile-dir positions
  int r1dQ[2];        // their qubits
  int r1lQ;           // R1 lane-gate qubit (at tid bit 5)
  int r1f[9];         // R1 thread-bit -> position (bits0-4 lowest free, bit5 = lane pos)
  u32 tinv[13];       // tau^{-1} local masks (raw)
  u32 cinv[13];       // mid: (tau^{-1} o A^{-1}) local; fin: full fwd masks
  u32 tL[13];         // Lmap(tinv)
  u32 cL[13];         // Lmap(cinv) (mid passes)
  u32 tCkL[3];        // chunk-bit affine masks of tau^{-1} (L-mapped local part)
  u32 fCk[3];         // readout: forward tau image of chunk basis (full 16-bit)
  u32 r1em[9];        // global gather masks (1<<qubit)
  u32 r1eL[9];        // LDS write masks (Lmap(1<<pos))
  u32 r1dm[2];        // dir global masks
  u32 r1dLm[2];       // dir LDS masks
};

template<int J>
__device__ __forceinline__ void gate16(float2 (&a)[16],
  float M0r,float M0i,float M1r,float M1i,float M2r,float M2i,float M3r,float M3i){
  #pragma unroll
  for (int i=0;i<16;i++){
    if ((i>>J)&1) continue;
    const int i1 = i|(1<<J);
    float ar=a[i].x, ai=a[i].y, br=a[i1].x, bi=a[i1].y;
    a[i].x  = M0r*ar - M0i*ai + M1r*br - M1i*bi;
    a[i].y  = M0r*ai + M0i*ar + M1r*bi + M1i*br;
    a[i1].x = M2r*ar - M2i*ai + M3r*br - M3i*bi;
    a[i1].y = M2r*ai + M2i*ar + M3r*bi + M3i*br;
  }
}

__device__ __forceinline__ void lane_gate16(float2 (&a)[16], int tid, int j,
  float r0,float i0,float r1,float i1,float r2,float i2,float r3,float i3){
  int bit = (tid >> j) & 1;
  float cAr = bit? r3 : r0, cAi = bit? i3 : i0;
  float cBr = bit? r2 : r1, cBi = bit? i2 : i1;
  #pragma unroll
  for (int i=0;i<16;i++){
    float tx = __shfl_xor(a[i].x, 1<<j);
    float ty = __shfl_xor(a[i].y, 1<<j);
    float ax = a[i].x, ay = a[i].y;
    a[i].x = cAr*ax - cAi*ay + cBr*tx - cBi*ty;
    a[i].y = cAr*ay + cAi*ax + cBr*ty + cBi*tx;
  }
}

#define APPLY16(J, SRC) { \
  int _s = (SRC); \
  float r0_=__shfl(mm0,_s), i0_=__shfl(mm1,_s), r1_=__shfl(mm2,_s), i1_=__shfl(mm3,_s); \
  float r2_=__shfl(mm4,_s), i2_=__shfl(mm5,_s), r3_=__shfl(mm6,_s), i3_=__shfl(mm7,_s); \
  gate16<J>(a, r0_,i0_,r1_,i1_,r2_,i2_,r3_,i3_); }

#define LANE16(J, SRC) { \
  int _s = (SRC); \
  float r0_=__shfl(mm0,_s), i0_=__shfl(mm1,_s), r1_=__shfl(mm2,_s), i1_=__shfl(mm3,_s); \
  float r2_=__shfl(mm4,_s), i2_=__shfl(mm5,_s), r3_=__shfl(mm6,_s), i3_=__shfl(mm7,_s); \
  lane_gate16(a, tid, (J), r0_,i0_,r1_,i1_,r2_,i2_,r3_,i3_); }

// Occupancy/register balance (rounds 5-6 evidence):
//   launch_bounds(512,4): compiler squeezed to 64 VGPR -> scratch spills (WRITE 3x), 16 waves/CU.
//   launch_bounds(512,2): 80 VGPR no spills, but only 8 waves/CU resident (occ 21%).
// waves_per_eu(4,4) pins the 4-waves/EU tier: VGPR budget 128 (no spill incentive),
// and 16 waves/CU (= the 2-block LDS limit). Best of both.
__global__ __launch_bounds__(NTHREADS)
__attribute__((amdgpu_waves_per_eu(4, 4)))
void qpass(const float* __restrict__ x, const float* __restrict__ w,
           float2* __restrict__ state, float* __restrict__ out, PD pd)
{
  __shared__ __align__(16) float2 st[NLOC];   // 64 KB
  const int tid = threadIdx.x;
  const u32 chunk = blockIdx.x;
  const int b = pd.b0 + blockIdx.y;
  float2* __restrict__ gst = state + ((size_t)b << NQ);

  // per-lane Rot matrices: lanes 0-15 = layerA (prev), 16-31 = layerB (cur)
  float mm0,mm1,mm2,mm3,mm4,mm5,mm6,mm7;
  {
    int lane = tid & 63;
    int q = lane & 15;
    int lay = ((lane>>4)&1) ? pd.layerB : pd.layerA;
    if (lay < 0) lay = 0;
    float phi = w[(lay*NQ+q)*3+0], th = w[(lay*NQ+q)*3+1], om = w[(lay*NQ+q)*3+2];
    float sh, ch; sincosf(0.5f*th, &sh, &ch);
    float spo, cpo; sincosf(-0.5f*(phi+om), &spo, &cpo);
    float smo, cmo; sincosf(-0.5f*(phi-om), &smo, &cmo);
    mm0 =  cpo*ch; mm1 =  spo*ch;
    mm2 = -cmo*sh; mm3 =  smo*sh;
    mm4 =  cmo*sh; mm5 =  smo*sh;
    mm6 =  cpo*ch; mm7 = -spo*ch;
  }

  // chunk-dependent affine part of tau^{-1} (L-mapped)
  u32 ckL = 0;
  if (chunk & 1) ckL ^= pd.tCkL[0];
  if (chunk & 2) ckL ^= pd.tCkL[1];
  if (chunk & 4) ckL ^= pd.tCkL[2];

  float2 a[16];

  // ================= R1: coalesced global gather + 3 prev-layer deferred Rots =====
  if (pd.mode != 1){
    u32 ebase = 0, lbL = 0;
    #pragma unroll
    for (int j=0;j<9;j++) if ((tid>>j)&1){ ebase ^= pd.r1em[j]; lbL ^= pd.r1eL[j]; }
    #pragma unroll
    for (int j=0;j<3;j++) if ((chunk>>j)&1) ebase ^= 1u<<pd.glb[j];
    #pragma unroll
    for (int g=0; g<4; g++){
      u32 full = ebase ^ ((g&1)?pd.r1dm[0]:0u) ^ (((g>>1)&1)?pd.r1dm[1]:0u);
      const float4* gp = (const float4*)(gst + full);
      float4 v0 = gp[0], v1 = gp[1];
      a[g*4+0] = make_float2(v0.x,v0.y); a[g*4+1] = make_float2(v0.z,v0.w);
      a[g*4+2] = make_float2(v1.x,v1.y); a[g*4+3] = make_float2(v1.z,v1.w);
    }
    APPLY16(2, pd.r1dQ[0]);
    APPLY16(3, pd.r1dQ[1]);
    LANE16(5, pd.r1lQ);

    if (pd.mode == 2){
      // -------- readout: |amp|^2, full forward masks in cinv; chunk via fCk --------
      float acc[NQ];
      #pragma unroll
      for (int q=0;q<NQ;q++) acc[q]=0.f;
      u32 nb = 0;
      #pragma unroll
      for (int j=0;j<9;j++) if ((tid>>j)&1) nb ^= pd.cinv[pd.r1f[j]];
      #pragma unroll
      for (int j=0;j<3;j++) if ((chunk>>j)&1) nb ^= pd.fCk[j];
      u32 cd0 = pd.cinv[pd.r1dPos[0]], cd1 = pd.cinv[pd.r1dPos[1]];
      #pragma unroll
      for (int g=0; g<4; g++){
        u32 n0 = nb ^ ((g&1)?cd0:0u) ^ (((g>>1)&1)?cd1:0u);
        #pragma unroll
        for (int e=0;e<4;e++){
          u32 n = n0 ^ ((e&1)?pd.cinv[0]:0u) ^ (((e>>1)&1)?pd.cinv[1]:0u);
          float2 v = a[g*4+e];
          float p = v.x*v.x + v.y*v.y;
          #pragma unroll
          for (int q=0;q<NQ;q++) acc[q] += ((n>>q)&1u) ? -p : p;
        }
      }
      #pragma unroll
      for (int q=0;q<NQ;q++){
        float v = acc[q];
        #pragma unroll
        for (int off=32; off; off>>=1) v += __shfl_xor(v, off);
        if ((tid & 63) == 0) atomicAdd(&out[b*NQ+q], v);
      }
      return;
    }

    // write tile to LDS (logical pre-tau layout)
    #pragma unroll
    for (int g=0; g<4; g++){
      u32 mL = lbL ^ ((g&1)?pd.r1dLm[0]:0u) ^ (((g>>1)&1)?pd.r1dLm[1]:0u);
      ((float4*)st)[(mL>>1)  ] = make_float4(a[g*4+0].x,a[g*4+0].y,a[g*4+1].x,a[g*4+1].y);
      ((float4*)st)[(mL>>1)+1] = make_float4(a[g*4+2].x,a[g*4+2].y,a[g*4+3].x,a[g*4+3].y);
    }
    __syncthreads();
  }

  // ================= R2: 10 gates (2 e + 2 dir + 6 lane) =================
  u32 sbL = ckL;
  #pragma unroll
  for (int j=0;j<9;j++) if ((tid>>j)&1) sbL ^= pd.tL[2+j];
  const u32 Ltd0 = pd.tL[11], Ltd1 = pd.tL[12], Le0 = pd.tL[0], Le1 = pd.tL[1];

  if (pd.mode == 1){
    // embed: product state directly in R2 layout (tau = identity at p=0)
    float ca[NQ], sa[NQ];
    #pragma unroll
    for (int q=0;q<NQ;q++){
      float aa = 1.57079632679489662f * x[b*NQ+q];
      sincosf(aa, &sa[q], &ca[q]);
    }
    float vt = 1.f;
    #pragma unroll
    for (int j=0;j<9;j++){ int q = pd.qop[2+j]; vt *= ((tid>>j)&1)? sa[q] : ca[q]; }
    #pragma unroll
    for (int j=0;j<3;j++){ int q = pd.glb[j]; vt *= ((chunk>>j)&1)? sa[q] : ca[q]; }
    float c0 = ca[pd.qop[0]], s0 = sa[pd.qop[0]], c1 = ca[pd.qop[1]], s1 = sa[pd.qop[1]];
    float cd0 = ca[pd.qop[11]], sd0 = sa[pd.qop[11]];
    float cd1 = ca[pd.qop[12]], sd1 = sa[pd.qop[12]];
    #pragma unroll
    for (int g=0; g<4; g++){
      float vg = vt * ((g&1)? sd0 : cd0) * (((g>>1)&1)? sd1 : cd1);
      a[g*4+0] = make_float2(vg*c0*c1, 0.f);
      a[g*4+1] = make_float2(vg*s0*c1, 0.f);
      a[g*4+2] = make_float2(vg*c0*s1, 0.f);
      a[g*4+3] = make_float2(vg*s0*s1, 0.f);
    }
  } else {
    #pragma unroll
    for (int g=0; g<4; g++){
      u32 sL = sbL ^ ((g&1)?Ltd0:0u) ^ (((g>>1)&1)?Ltd1:0u);
      a[g*4+0] = st[sL];
      a[g*4+1] = st[sL^Le0];
      a[g*4+2] = st[sL^Le1];
      a[g*4+3] = st[sL^Le0^Le1];
    }
  }

  APPLY16(0, 16+pd.qop[0]);  APPLY16(1, 16+pd.qop[1]);
  APPLY16(2, 16+pd.qop[11]); APPLY16(3, 16+pd.qop[12]);
  #pragma unroll
  for (int j=0;j<6;j++){
    LANE16(j, 16+pd.qop[2+j]);
  }

  #pragma unroll
  for (int g=0; g<4; g++){
    u32 sL = sbL ^ ((g&1)?Ltd0:0u) ^ (((g>>1)&1)?Ltd1:0u);
    st[sL]         = a[g*4+0];
    st[sL^Le0]     = a[g*4+1];
    st[sL^Le1]     = a[g*4+2];
    st[sL^Le0^Le1] = a[g*4+3];
  }
  __syncthreads();

  // ================= R2b: 3 gates (dirs at pos 8,9 + lane gate at pos 10) =====
  // thread bits: bit0->pos10, bits1..6->pos2..7, bit7->pos11, bit8->pos12
  {
    u32 s2L = ckL;
    if (tid & 1) s2L ^= pd.tL[10];
    #pragma unroll
    for (int j=1;j<7;j++) if ((tid>>j)&1) s2L ^= pd.tL[1+j];
    if ((tid>>7)&1) s2L ^= pd.tL[11];
    if ((tid>>8)&1) s2L ^= pd.tL[12];
    const u32 LD0 = pd.tL[8], LD1 = pd.tL[9];
    #pragma unroll
    for (int g=0; g<4; g++){
      u32 sL = s2L ^ ((g&1)?LD0:0u) ^ (((g>>1)&1)?LD1:0u);
      a[g*4+0] = st[sL];
      a[g*4+1] = st[sL^Le0];
      a[g*4+2] = st[sL^Le1];
      a[g*4+3] = st[sL^Le0^Le1];
    }
    APPLY16(2, 16+pd.qop[8]); APPLY16(3, 16+pd.qop[9]);
    LANE16(0, 16+pd.qop[10]);
    #pragma unroll
    for (int g=0; g<4; g++){
      u32 sL = s2L ^ ((g&1)?LD0:0u) ^ (((g>>1)&1)?LD1:0u);
      st[sL]         = a[g*4+0];
      st[sL^Le0]     = a[g*4+1];
      st[sL^Le1]     = a[g*4+2];
      st[sL^Le0^Le1] = a[g*4+3];
    }
    __syncthreads();
  }

  // ================= R3: coalesced stage-out, (tau^-1 o A^-1) fold on LDS read =====
  {
    u32 ctL = ckL, etid = 0;
    #pragma unroll
    for (int j=0;j<9;j++) if ((tid>>j)&1){ ctL ^= pd.cL[2+j]; etid ^= 1u<<pd.qop[2+j]; }
    #pragma unroll
    for (int j=0;j<3;j++) if ((chunk>>j)&1) etid ^= 1u<<pd.glb[j];
    const u32 Lc0 = pd.cL[0], Lc1 = pd.cL[1];
    const u32 Lc11 = pd.cL[11], Lc12 = pd.cL[12];
    const u32 q11 = 1u<<pd.qop[11], q12 = 1u<<pd.qop[12];
    #pragma unroll
    for (int j=0;j<4;j++){
      u32 srcL  = ctL  ^ ((j&1)?Lc11:0u) ^ (((j>>1)&1)?Lc12:0u);
      u32 ofull = etid ^ ((j&1)?q11:0u)  ^ (((j>>1)&1)?q12:0u);
      float2 vv0 = st[srcL];
      float2 vv1 = st[srcL^Lc0];
      float2 vv2 = st[srcL^Lc1];
      float2 vv3 = st[srcL^Lc0^Lc1];
      float4* gp = (float4*)(gst + ofull);
      gp[0] = make_float4(vv0.x,vv0.y,vv1.x,vv1.y);
      gp[1] = make_float4(vv2.x,vv2.y,vv3.x,vv3.y);
    }
  }
}

// ======================= host side =======================
// Hand-verified schedule: globals high (coalesced), deferred targets always local
// in the next pass; global-CONTROL deferred gates handled via tCkL chunk masks.
static const int Gs[9][3] = {
  {13,14,15},{8,10,12},{11,13,15},{8,9,10},{7,11,15},{8,9,10},{11,12,13},{8,9,10},{13,14,15}
};
static const int Dlen[8] = {4,5,7,9,8,10,8,6};
static const int Dl[8][10] = {
  {12,13,14,15,0,0,0,0,0,0},
  {6,8,10,12,14,0,0,0,0,0},
  {8,10,11,12,13,14,15,0,0,0},
  {4,5,6,8,9,10,12,13,14,0},
  {2,6,7,10,11,12,13,15,0,0},
  {2,3,4,8,9,10,12,13,14,15},
  {4,5,6,11,12,13,14,15,0,0},
  {0,1,2,8,9,10,0,0,0,0},
};

static inline u32 apply_cnot_idx(u32 v, int c, int t){ return v ^ (((v>>c)&1u)<<t); }
static inline u32 h_swz(u32 q){ return q ^ ((q>>3)&7u); }
static inline u32 h_Lmap(u32 m){ return (h_swz(m>>2)<<2) | (m&3u); }

extern "C" void kernel_launch(void* const* d_in, const int* in_sizes, int n_in,
                              void* d_out, int out_size, void* d_ws, size_t ws_size,
                              hipStream_t stream)
{
  (void)in_sizes; (void)n_in; (void)ws_size;
  const float* x = (const float*)d_in[0];
  const float* w = (const float*)d_in[1];
  float* out = (float*)d_out;
  float2* state = (float2*)d_ws;   // 512 * 65536 * 8B = 256 MiB

  hipMemsetAsync(d_out, 0, (size_t)out_size*sizeof(float), stream);

  for (int grp=0; grp<NGROUP; grp++){
    for (int p=0; p<9; p++){
      PD pd; memset(&pd, 0, sizeof(pd));
      pd.layerA = p-1;
      pd.layerB = (p<=7)? p : -1;
      pd.mode = (p==0)? 1 : ((p==8)? 2 : 0);
      pd.b0 = grp*GROUPB;

      u32 gm = 0;
      for (int i=0;i<3;i++){ pd.glb[i] = Gs[p][i]; gm |= 1u<<Gs[p][i]; }
      int np=0;
      for (int q=0;q<16;q++) if (!((gm>>q)&1u)) pd.qop[np++] = q;

      // R1 geometry (prev-layer deferred Rot gates)
      if (p >= 1){
        int pos[3], qq[3];
        for (int i=0;i<3;i++){
          int q = Gs[p-1][i]; qq[i] = q;
          int c=0; for (int k=0;k<q;k++) if ((gm>>k)&1u) c++;
          pos[i] = q - c;
        }
        for (int i=0;i<3;i++) for (int k=i+1;k<3;k++)
          if (pos[k] < pos[i]){ int t=pos[i];pos[i]=pos[k];pos[k]=t; t=qq[i];qq[i]=qq[k];qq[k]=t; }
        pd.r1lQ = qq[0];
        pd.r1dPos[0]=pos[1]; pd.r1dQ[0]=qq[1];
        pd.r1dPos[1]=pos[2]; pd.r1dQ[1]=qq[2];
        int free_[9], nf=0;
        for (int pp=2; pp<13; pp++)
          if (pp!=pos[0] && pp!=pos[1] && pp!=pos[2]) free_[nf++]=pp;   // 8 entries
        for (int j=0;j<5;j++) pd.r1f[j]=free_[j];   // bits 0-4: lowest positions
        pd.r1f[5]=pos[0];                            // bit 5: lane-gate position
        for (int j=0;j<3;j++) pd.r1f[6+j]=free_[5+j];
      } else {
        pd.r1lQ = 0;
        pd.r1dPos[0]=11; pd.r1dQ[0]=0;
        pd.r1dPos[1]=12; pd.r1dQ[1]=0;
        for (int j=0;j<5;j++) pd.r1f[j]=2+j;
        pd.r1f[5]=10; pd.r1f[6]=7; pd.r1f[7]=8; pd.r1f[8]=9;
      }

      // tinv: tau^{-1} on local basis (deferred CNOTs of layer p-1, reverse order)
      if (p == 0){
        for (int bp=0;bp<13;bp++) pd.tinv[bp] = 1u<<bp;
        for (int j=0;j<3;j++) pd.tCkL[j] = 0u;
      } else {
        int r = p;  // layer (p-1) has r = p
        for (int bp=0;bp<13;bp++){
          u32 v = 1u<<pd.qop[bp];
          for (int i=Dlen[p-1]-1;i>=0;i--){ int c=Dl[p-1][i]; v = apply_cnot_idx(v, c, (c+r)&15); }
          u32 lv=0; for (int rr=0;rr<13;rr++) lv |= ((v>>pd.qop[rr])&1u)<<rr;
          pd.tinv[bp] = lv;
        }
        // chunk-basis affine part: image of chunk qubit under tau^{-1}, local component
        for (int j=0;j<3;j++){
          u32 v = 1u<<pd.glb[j];
          for (int i=Dlen[p-1]-1;i>=0;i--){ int c=Dl[p-1][i]; v = apply_cnot_idx(v, c, (c+r)&15); }
          v &= ~(1u<<pd.glb[j]);      // chunk bit passes through; keep local part
          u32 lv=0; for (int rr=0;rr<13;rr++) lv |= ((v>>pd.qop[rr])&1u)<<rr;
          pd.tCkL[j] = h_Lmap(lv);
        }
      }

      // cinv
      if (p <= 7){
        int r = p+1;
        bool inD[16]; for (int i=0;i<16;i++) inD[i]=false;
        for (int i=0;i<Dlen[p];i++) inD[Dl[p][i]] = true;
        int A[16], na=0;
        for (int i=0;i<16;i++) if (!inD[i]) A[na++]=i;
        for (int bp=0;bp<13;bp++){
          u32 v = 1u<<pd.qop[bp];
          for (int i=na-1;i>=0;i--){ int c=A[i]; v = apply_cnot_idx(v, c, (c+r)&15); }
          if (p >= 1){
            int rp = p;
            for (int i=Dlen[p-1]-1;i>=0;i--){ int c=Dl[p-1][i]; v = apply_cnot_idx(v, c, (c+rp)&15); }
          }
          u32 lv=0; for (int rr=0;rr<13;rr++) lv |= ((v>>pd.qop[rr])&1u)<<rr;
          pd.cinv[bp] = lv;
        }
        for (int j=0;j<3;j++) pd.fCk[j] = 0u;
      } else {
        // readout: full forward tau (D_7 ascending, r=8), uncompressed 16-bit
        for (int bp=0;bp<13;bp++){
          u32 v = 1u<<pd.qop[bp];
          for (int i=0;i<Dlen[7];i++){ int c=Dl[7][i]; v = apply_cnot_idx(v, c, (c+8)&15); }
          pd.cinv[bp] = v;
        }
        for (int j=0;j<3;j++){
          u32 v = 1u<<pd.glb[j];
          for (int i=0;i<Dlen[7];i++){ int c=Dl[7][i]; v = apply_cnot_idx(v, c, (c+8)&15); }
          pd.fCk[j] = v;
        }
      }

      // L-mapped precomputes
      for (int k=0;k<13;k++){
        pd.tL[k] = h_Lmap(pd.tinv[k]);
        pd.cL[k] = (p<=7) ? h_Lmap(pd.cinv[k]) : 0u;
      }
      for (int j=0;j<9;j++){
        pd.r1em[j] = 1u<<pd.qop[pd.r1f[j]];
        pd.r1eL[j] = h_Lmap(1u<<pd.r1f[j]);
      }
      for (int j=0;j<2;j++){
        pd.r1dm[j]  = 1u<<pd.qop[pd.r1dPos[j]];
        pd.r1dLm[j] = h_Lmap(1u<<pd.r1dPos[j]);
      }

      hipLaunchKernelGGL(qpass, dim3(NCHUNK, GROUPB), dim3(NTHREADS), 0, stream,
                         x, w, state, out, pd);
    }
  }
}